// Round 1
// baseline (1317.344 us; speedup 1.0000x reference)
//
#include <hip/hip_runtime.h>
#include <math.h>

// Problem constants
#define NB   32768   // batch
#define AG   6       // agents
#define LL   225     // obs len
#define DD   128     // enc dim
#define EE   5       // visible agents
#define NOUT 5       // actions
#define ADIM 64      // attn dim

// Workspace layout (floats)
#define WS_M   0        // 128*128  : M = q_w @ k_w^T / 8
#define WS_W1T 16384    // 5*128    : W1t[o*128+d] = sum_e fc_w[(e*128+d)*5+o]
#define WS_F2T 17024    // 25*128   : F2t[(e*5+o)*128+d] = fc_w[(640+e*128+d)*5+o]

__global__ void precompute_kernel(const float* __restrict__ q_w,
                                  const float* __restrict__ k_w,
                                  const float* __restrict__ fc_w,
                                  float* __restrict__ ws) {
    int b = blockIdx.x;
    int t = threadIdx.x;
    if (b < 128) {
        // M[b][t] = (1/8) * sum_j q_w[b][j] * k_w[t][j]
        float s = 0.f;
        #pragma unroll 8
        for (int j = 0; j < ADIM; ++j)
            s = fmaf(q_w[b * ADIM + j], k_w[t * ADIM + j], s);
        ws[WS_M + b * 128 + t] = s * 0.125f;
    } else {
        int d = t;
        #pragma unroll
        for (int o = 0; o < NOUT; ++o) {
            float s = 0.f;
            #pragma unroll
            for (int e = 0; e < EE; ++e)
                s += fc_w[(e * 128 + d) * NOUT + o];
            ws[WS_W1T + o * 128 + d] = s;
            #pragma unroll
            for (int e = 0; e < EE; ++e)
                ws[WS_F2T + (e * 5 + o) * 128 + d] = fc_w[(640 + e * 128 + d) * NOUT + o];
        }
    }
}

// One wave processes 4 samples. Lane owns enc columns {2*lane, 2*lane+1}.
__global__ __launch_bounds__(256)
void policy_kernel(const float* __restrict__ obs,
                   const float* __restrict__ enc_w,
                   const float* __restrict__ enc_b,
                   const float* __restrict__ fc_b,
                   const float* __restrict__ u,
                   const float* __restrict__ ws,
                   int* __restrict__ out) {
    __shared__ float lds_e[4][4 * AG * DD];   // 4 waves * 4 samples * 6 agents * 128 = 48 KiB

    const int lane = threadIdx.x & 63;
    const int wv   = __builtin_amdgcn_readfirstlane(threadIdx.x >> 6);
    const int gw   = blockIdx.x * 4 + wv;
    const int s0   = gw * 4;                  // first of 4 samples for this wave
    const int c0   = lane * 2;                // enc columns c0, c0+1

    // ---------------- Phase 1: encoder (relu(obs @ enc_w + enc_b)) ----------------
    const float* obs_base = obs + (size_t)s0 * (AG * LL);   // wave-uniform pointer
    float acc[4][AG][2];
    #pragma unroll
    for (int s = 0; s < 4; ++s)
        #pragma unroll
        for (int a = 0; a < AG; ++a) { acc[s][a][0] = 0.f; acc[s][a][1] = 0.f; }

    for (int l = 0; l < LL; ++l) {
        const float2 w = *(const float2*)(enc_w + (size_t)l * DD + c0);
        #pragma unroll
        for (int s = 0; s < 4; ++s) {
            #pragma unroll
            for (int a = 0; a < AG; ++a) {
                const float ov = obs_base[(s * AG + a) * LL + l];   // uniform -> s_load
                acc[s][a][0] = fmaf(ov, w.x, acc[s][a][0]);
                acc[s][a][1] = fmaf(ov, w.y, acc[s][a][1]);
            }
        }
    }

    const float b0 = enc_b[c0];
    const float b1 = enc_b[c0 + 1];
    #pragma unroll
    for (int s = 0; s < 4; ++s) {
        #pragma unroll
        for (int a = 0; a < AG; ++a) {
            float2 v;
            v.x = fmaxf(acc[s][a][0] + b0, 0.f);
            v.y = fmaxf(acc[s][a][1] + b1, 0.f);
            *(float2*)&lds_e[wv][(s * AG + a) * DD + c0] = v;
        }
    }
    __syncthreads();

    // ---------------- Phase 2a: t = ag_e @ M ; scores ; softmax ----------------
    const float* Mw = ws + WS_M;
    float t0[4] = {0.f, 0.f, 0.f, 0.f};
    float t1[4] = {0.f, 0.f, 0.f, 0.f};
    for (int d = 0; d < DD; ++d) {
        const float2 m = *(const float2*)(Mw + (size_t)d * 128 + c0);
        #pragma unroll
        for (int s = 0; s < 4; ++s) {
            const float agv = lds_e[wv][(s * AG + 0) * DD + d];   // broadcast read
            t0[s] = fmaf(agv, m.x, t0[s]);
            t1[s] = fmaf(agv, m.y, t1[s]);
        }
    }

    float sc[4][EE];
    #pragma unroll
    for (int s = 0; s < 4; ++s) {
        #pragma unroll
        for (int e = 0; e < EE; ++e) {
            const float2 v = *(const float2*)&lds_e[wv][(s * AG + 1 + e) * DD + c0];
            sc[s][e] = t0[s] * v.x + t1[s] * v.y;
        }
    }
    #pragma unroll
    for (int off = 32; off > 0; off >>= 1) {
        #pragma unroll
        for (int s = 0; s < 4; ++s)
            #pragma unroll
            for (int e = 0; e < EE; ++e)
                sc[s][e] += __shfl_xor(sc[s][e], off, 64);
    }

    float alpha[4][EE];
    #pragma unroll
    for (int s = 0; s < 4; ++s) {
        float mx = sc[s][0];
        #pragma unroll
        for (int e = 1; e < EE; ++e) mx = fmaxf(mx, sc[s][e]);
        float sum = 0.f;
        #pragma unroll
        for (int e = 0; e < EE; ++e) { alpha[s][e] = expf(sc[s][e] - mx); sum += alpha[s][e]; }
        const float inv = 1.f / sum;
        #pragma unroll
        for (int e = 0; e < EE; ++e) alpha[s][e] *= inv;
    }

    // ---------------- Phase 2b: logits ----------------
    const float* W1t = ws + WS_W1T;
    const float* F2t = ws + WS_F2T;
    float Lg[4][NOUT];
    #pragma unroll
    for (int s = 0; s < 4; ++s)
        #pragma unroll
        for (int o = 0; o < NOUT; ++o) Lg[s][o] = 0.f;

    float2 ag2[4];
    #pragma unroll
    for (int s = 0; s < 4; ++s)
        ag2[s] = *(const float2*)&lds_e[wv][(s * AG + 0) * DD + c0];

    #pragma unroll
    for (int o = 0; o < NOUT; ++o) {
        const float2 w1 = *(const float2*)(W1t + o * 128 + c0);
        #pragma unroll
        for (int s = 0; s < 4; ++s)
            Lg[s][o] = fmaf(ag2[s].x, w1.x, fmaf(ag2[s].y, w1.y, Lg[s][o]));
    }

    #pragma unroll
    for (int e = 0; e < EE; ++e) {
        float2 vv[4];
        #pragma unroll
        for (int s = 0; s < 4; ++s) {
            const float2 v = *(const float2*)&lds_e[wv][(s * AG + 1 + e) * DD + c0];
            vv[s].x = alpha[s][e] * v.x;
            vv[s].y = alpha[s][e] * v.y;
        }
        #pragma unroll
        for (int o = 0; o < NOUT; ++o) {
            const float2 f2 = *(const float2*)(F2t + (e * 5 + o) * 128 + c0);
            #pragma unroll
            for (int s = 0; s < 4; ++s)
                Lg[s][o] = fmaf(vv[s].x, f2.x, fmaf(vv[s].y, f2.y, Lg[s][o]));
        }
    }

    #pragma unroll
    for (int off = 32; off > 0; off >>= 1) {
        #pragma unroll
        for (int s = 0; s < 4; ++s)
            #pragma unroll
            for (int o = 0; o < NOUT; ++o)
                Lg[s][o] += __shfl_xor(Lg[s][o], off, 64);
    }

    // ---------------- Gumbel + argmax (softmax/tau are monotone -> skip) ----------------
    #pragma unroll
    for (int s = 0; s < 4; ++s) {
        float best = -1e30f;
        int   bi   = 0;
        #pragma unroll
        for (int o = 0; o < NOUT; ++o) {
            const float uu = u[(size_t)(s0 + s) * NOUT + o];
            const float g  = -logf(-logf(uu + 1e-10f) + 1e-10f);
            const float y  = Lg[s][o] + fc_b[o] + g;
            if (y > best) { best = y; bi = o; }   // strict > keeps first max (np.argmax)
        }
        if (lane == s) out[s0 + s] = bi;
    }
}

extern "C" void kernel_launch(void* const* d_in, const int* in_sizes, int n_in,
                              void* d_out, int out_size, void* d_ws, size_t ws_size,
                              hipStream_t stream) {
    const float* obs   = (const float*)d_in[0];
    const float* enc_w = (const float*)d_in[1];
    const float* enc_b = (const float*)d_in[2];
    const float* q_w   = (const float*)d_in[3];
    const float* k_w   = (const float*)d_in[4];
    const float* fc_w  = (const float*)d_in[5];
    const float* fc_b  = (const float*)d_in[6];
    const float* uu    = (const float*)d_in[7];
    float* ws = (float*)d_ws;
    int*   po = (int*)d_out;

    precompute_kernel<<<129, 128, 0, stream>>>(q_w, k_w, fc_w, ws);
    policy_kernel<<<NB / 16, 256, 0, stream>>>(obs, enc_w, enc_b, fc_b, uu, ws, po);
}

// Round 2
// 559.213 us; speedup vs baseline: 2.3557x; 2.3557x over previous
//
#include <hip/hip_runtime.h>
#include <math.h>

// Problem constants
#define NB   32768
#define AG   6
#define LL   225
#define DD   128
#define EE   5
#define NOUT 5
#define ADIM 64

// Workspace layout (floats)
#define WS_M   0        // 128*128  : M = q_w @ k_w^T / 8   (row-major [d][c])
#define WS_W1T 16384    // 5*128    : W1t[o*128+d] = sum_e fc_w[(e*128+d)*5+o]
#define WS_F2T 17024    // 25*128   : F2t[(e*5+o)*128+d] = fc_w[(640+e*128+d)*5+o]

// Fused-kernel tiling
#define SBLK 16         // samples per block (4 waves x 4 samples)
#define RWS  96         // obs rows per block = SBLK*AG
#define LC   75         // l-chunk (225 = 3*75)
#define OST  76         // obs LDS row stride (pad: 6*76 % 32 = 8 -> 4 groups on disjoint banks)
#define ENCW_OFF 7296   // float offset of enc_w chunk in LDS (96*76)
#define LDS_FLOATS 17024  // 7296 + 76*128 = 68,096 B -> 2 blocks/CU

__global__ void precompute_kernel(const float* __restrict__ q_w,
                                  const float* __restrict__ k_w,
                                  const float* __restrict__ fc_w,
                                  float* __restrict__ ws) {
    int b = blockIdx.x;
    int t = threadIdx.x;
    if (b < 128) {
        float s = 0.f;
        #pragma unroll 8
        for (int j = 0; j < ADIM; ++j)
            s = fmaf(q_w[b * ADIM + j], k_w[t * ADIM + j], s);
        ws[WS_M + b * 128 + t] = s * 0.125f;
    } else {
        int d = t;
        #pragma unroll
        for (int o = 0; o < NOUT; ++o) {
            float s = 0.f;
            #pragma unroll
            for (int e = 0; e < EE; ++e)
                s += fc_w[(e * 128 + d) * NOUT + o];
            ws[WS_W1T + o * 128 + d] = s;
            #pragma unroll
            for (int e = 0; e < EE; ++e)
                ws[WS_F2T + (e * 5 + o) * 128 + d] = fc_w[(640 + e * 128 + d) * NOUT + o];
        }
    }
}

// Block: 256 threads / 4 waves, 16 samples. Wave w owns samples 4w..4w+3.
// Encoder: lane group g=lane>>4 -> sample 4w+g; agent = row within group;
//          lane col set {4i..4i+3} u {64+4i..64+4i+3}, i = lane&15.
__global__ __launch_bounds__(256, 2)
void policy_kernel(const float* __restrict__ obs,
                   const float* __restrict__ enc_w,
                   const float* __restrict__ enc_b,
                   const float* __restrict__ fc_b,
                   const float* __restrict__ u,
                   const float* __restrict__ ws,
                   int* __restrict__ out) {
    __shared__ float lds[LDS_FLOATS];
    const int tid  = threadIdx.x;
    const int lane = tid & 63;
    const int w    = tid >> 6;
    const int g    = lane >> 4;
    const int ii   = lane & 15;
    const int bs0  = blockIdx.x * SBLK;

    float acc[AG][8];
    #pragma unroll
    for (int a = 0; a < AG; ++a)
        #pragma unroll
        for (int c = 0; c < 8; ++c) acc[a][c] = 0.f;

    const float* obs_blk = obs + (size_t)bs0 * (AG * LL);
    const int rowbase = (4 * w + g) * AG;   // block-local obs row of agent 0 for my sample

    for (int chunk = 0; chunk < 3; ++chunk) {
        const int l0 = chunk * LC;
        // ---- stage obs chunk: 96 rows x 75 floats (coalesced dword) ----
        #pragma unroll 1
        for (int k = 0; k < 29; ++k) {
            int idx = tid + k * 256;
            if (idx < RWS * LC) {
                int row = idx / LC;
                int col = idx - row * LC;
                lds[row * OST + col] = obs_blk[row * LL + l0 + col];
            }
        }
        // zero pads so the 19th quad multiplies by 0 instead of garbage
        if (tid < RWS) lds[tid * OST + LC] = 0.f;
        if (tid >= 96 && tid < 96 + DD) lds[ENCW_OFF + LC * DD + (tid - 96)] = 0.f;
        // ---- stage enc_w chunk: 75 x 128 floats (coalesced float4) ----
        {
            const float4* src = (const float4*)(enc_w + (size_t)l0 * DD);
            #pragma unroll 1
            for (int k = 0; k < 10; ++k) {
                int idx = tid + k * 256;
                if (idx < (LC * DD) / 4)
                    *(float4*)&lds[ENCW_OFF + idx * 4] = src[idx];
            }
        }
        __syncthreads();

        // ---- compute: 19 l-quads (76 l's, last col padded with zeros) ----
        for (int q = 0; q < 19; ++q) {
            const int lq = 4 * q;
            float ew[4][8];
            #pragma unroll
            for (int dl = 0; dl < 4; ++dl) {
                float4 lo = *(const float4*)&lds[ENCW_OFF + (lq + dl) * DD + 4 * ii];
                float4 hi = *(const float4*)&lds[ENCW_OFF + (lq + dl) * DD + 64 + 4 * ii];
                ew[dl][0] = lo.x; ew[dl][1] = lo.y; ew[dl][2] = lo.z; ew[dl][3] = lo.w;
                ew[dl][4] = hi.x; ew[dl][5] = hi.y; ew[dl][6] = hi.z; ew[dl][7] = hi.w;
            }
            #pragma unroll
            for (int a = 0; a < AG; ++a) {
                float4 ov4 = *(const float4*)&lds[(rowbase + a) * OST + lq];
                float ov[4] = {ov4.x, ov4.y, ov4.z, ov4.w};
                #pragma unroll
                for (int dl = 0; dl < 4; ++dl)
                    #pragma unroll
                    for (int c = 0; c < 8; ++c)
                        acc[a][c] = fmaf(ov[dl], ew[dl][c], acc[a][c]);
            }
        }
        __syncthreads();   // also guards the enc-region overwrite below (last iter)
    }

    // ---- epilogue: bias + relu -> enc in LDS [16][6][128] ----
    {
        float4 bA = *(const float4*)&enc_b[4 * ii];
        float4 bB = *(const float4*)&enc_b[64 + 4 * ii];
        const int samp = 4 * w + g;
        #pragma unroll
        for (int a = 0; a < AG; ++a) {
            float4 vA, vB;
            vA.x = fmaxf(acc[a][0] + bA.x, 0.f);
            vA.y = fmaxf(acc[a][1] + bA.y, 0.f);
            vA.z = fmaxf(acc[a][2] + bA.z, 0.f);
            vA.w = fmaxf(acc[a][3] + bA.w, 0.f);
            vB.x = fmaxf(acc[a][4] + bB.x, 0.f);
            vB.y = fmaxf(acc[a][5] + bB.y, 0.f);
            vB.z = fmaxf(acc[a][6] + bB.z, 0.f);
            vB.w = fmaxf(acc[a][7] + bB.w, 0.f);
            *(float4*)&lds[(samp * AG + a) * DD + 4 * ii]      = vA;
            *(float4*)&lds[(samp * AG + a) * DD + 64 + 4 * ii] = vB;
        }
    }
    // Each wave reads back only its own samples' enc -> no __syncthreads needed
    // (compiler orders same-wave LDS store->load via lgkmcnt).

    // ---- phase 2a: t = ag_e @ M (per-lane col pair c0..c0+1) ----
    const int c0 = 2 * lane;
    float t0[4] = {0.f, 0.f, 0.f, 0.f};
    float t1[4] = {0.f, 0.f, 0.f, 0.f};
    const float* Mw = ws + WS_M;
    #pragma unroll 1
    for (int dq = 0; dq < 32; ++dq) {
        const int d = 4 * dq;
        float2 m[4];
        #pragma unroll
        for (int dl = 0; dl < 4; ++dl)
            m[dl] = *(const float2*)&Mw[(size_t)(d + dl) * DD + c0];
        #pragma unroll
        for (int j = 0; j < 4; ++j) {
            float4 ag4 = *(const float4*)&lds[((4 * w + j) * AG) * DD + d];
            t0[j] = fmaf(ag4.x, m[0].x, t0[j]); t1[j] = fmaf(ag4.x, m[0].y, t1[j]);
            t0[j] = fmaf(ag4.y, m[1].x, t0[j]); t1[j] = fmaf(ag4.y, m[1].y, t1[j]);
            t0[j] = fmaf(ag4.z, m[2].x, t0[j]); t1[j] = fmaf(ag4.z, m[2].y, t1[j]);
            t0[j] = fmaf(ag4.w, m[3].x, t0[j]); t1[j] = fmaf(ag4.w, m[3].y, t1[j]);
        }
    }

    // ---- scores + softmax ----
    float v2x[4][EE], v2y[4][EE], sc[4][EE];
    #pragma unroll
    for (int j = 0; j < 4; ++j)
        #pragma unroll
        for (int e = 0; e < EE; ++e) {
            float2 v = *(const float2*)&lds[((4 * w + j) * AG + 1 + e) * DD + c0];
            v2x[j][e] = v.x; v2y[j][e] = v.y;
            sc[j][e] = t0[j] * v.x + t1[j] * v.y;
        }
    #pragma unroll
    for (int off = 32; off > 0; off >>= 1)
        #pragma unroll
        for (int j = 0; j < 4; ++j)
            #pragma unroll
            for (int e = 0; e < EE; ++e)
                sc[j][e] += __shfl_xor(sc[j][e], off, 64);

    float alpha[4][EE];
    #pragma unroll
    for (int j = 0; j < 4; ++j) {
        float mx = sc[j][0];
        #pragma unroll
        for (int e = 1; e < EE; ++e) mx = fmaxf(mx, sc[j][e]);
        float sum = 0.f;
        #pragma unroll
        for (int e = 0; e < EE; ++e) { alpha[j][e] = expf(sc[j][e] - mx); sum += alpha[j][e]; }
        const float inv = 1.f / sum;
        #pragma unroll
        for (int e = 0; e < EE; ++e) alpha[j][e] *= inv;
    }

    // ---- phase 2b: logits ----
    float Lg[4][NOUT];
    #pragma unroll
    for (int j = 0; j < 4; ++j)
        #pragma unroll
        for (int o = 0; o < NOUT; ++o) Lg[j][o] = 0.f;

    {
        float2 w1[NOUT];
        #pragma unroll
        for (int o = 0; o < NOUT; ++o)
            w1[o] = *(const float2*)&ws[WS_W1T + o * DD + c0];
        #pragma unroll
        for (int j = 0; j < 4; ++j) {
            float2 a2 = *(const float2*)&lds[((4 * w + j) * AG) * DD + c0];
            #pragma unroll
            for (int o = 0; o < NOUT; ++o)
                Lg[j][o] = fmaf(a2.x, w1[o].x, fmaf(a2.y, w1[o].y, Lg[j][o]));
        }
    }
    #pragma unroll
    for (int e = 0; e < EE; ++e) {
        float wx[4], wy[4];
        #pragma unroll
        for (int j = 0; j < 4; ++j) { wx[j] = alpha[j][e] * v2x[j][e]; wy[j] = alpha[j][e] * v2y[j][e]; }
        #pragma unroll
        for (int o = 0; o < NOUT; ++o) {
            float2 f2 = *(const float2*)&ws[WS_F2T + (e * NOUT + o) * DD + c0];
            #pragma unroll
            for (int j = 0; j < 4; ++j)
                Lg[j][o] = fmaf(wx[j], f2.x, fmaf(wy[j], f2.y, Lg[j][o]));
        }
    }
    #pragma unroll
    for (int off = 32; off > 0; off >>= 1)
        #pragma unroll
        for (int j = 0; j < 4; ++j)
            #pragma unroll
            for (int o = 0; o < NOUT; ++o)
                Lg[j][o] += __shfl_xor(Lg[j][o], off, 64);

    // ---- Gumbel + argmax (monotone -> skip softmax/tau) ----
    float myLg = 0.f;
    #pragma unroll
    for (int j = 0; j < 4; ++j)
        #pragma unroll
        for (int o = 0; o < NOUT; ++o)
            if (lane == j * NOUT + o) myLg = Lg[j][o];
    const int ul = (lane < 20) ? lane : 0;
    const float uu  = u[(size_t)(bs0 + 4 * w) * NOUT + ul];
    const float gmb = -logf(-logf(uu + 1e-10f) + 1e-10f);
    const float fb  = fc_b[ul % NOUT];
    const float y   = myLg + fb + gmb;

    const int s = (lane < 4) ? lane : 0;
    float best = -1e30f; int bi = 0;
    #pragma unroll
    for (int o = 0; o < NOUT; ++o) {
        float yo = __shfl(y, s * NOUT + o, 64);
        if (yo > best) { best = yo; bi = o; }   // strict > keeps first max (np.argmax)
    }
    if (lane < 4) out[bs0 + 4 * w + lane] = bi;
}

extern "C" void kernel_launch(void* const* d_in, const int* in_sizes, int n_in,
                              void* d_out, int out_size, void* d_ws, size_t ws_size,
                              hipStream_t stream) {
    const float* obs   = (const float*)d_in[0];
    const float* enc_w = (const float*)d_in[1];
    const float* enc_b = (const float*)d_in[2];
    const float* q_w   = (const float*)d_in[3];
    const float* k_w   = (const float*)d_in[4];
    const float* fc_w  = (const float*)d_in[5];
    const float* fc_b  = (const float*)d_in[6];
    const float* uu    = (const float*)d_in[7];
    float* ws = (float*)d_ws;
    int*   po = (int*)d_out;

    precompute_kernel<<<129, 128, 0, stream>>>(q_w, k_w, fc_w, ws);
    policy_kernel<<<NB / SBLK, 256, 0, stream>>>(obs, enc_w, enc_b, fc_b, uu, ws, po);
}